// Round 11
// baseline (1252.334 us; speedup 1.0000x reference)
//
#include <hip/hip_runtime.h>
#include <stdint.h>

typedef unsigned short u16;
typedef __attribute__((ext_vector_type(8))) short bf16x8;   // 8 bf16 = 4 VGPRs (MFMA A/B frag)
typedef __attribute__((ext_vector_type(4))) float f32x4;    // MFMA C/D frag

#define NNODES 20000
#define EM 120000
#define EC 20000
#define LDIM 128
#define MT 32          // rows per block (enc/dec/node kernels)
#define MT2 64         // rows per block (edge kernel, 512 threads)
#define A_STR 392      // concat LDS stride in shorts (384+8 pad -> 4-bank shift/row)
#define X_STR 264      // edge x-stage stride (256+8 pad -> 4-bank shift/row)
#define H_STR 136      // 128+8 pad
#define D_STR 132      // f32 delta stride (128+4 pad)

__device__ __forceinline__ u16 f2bf(float f){
  uint32_t b = __float_as_uint(f);
  b += 0x7FFF + ((b >> 16) & 1);          // RNE
  return (u16)(b >> 16);
}

__device__ __forceinline__ f32x4 mfma16(bf16x8 a, bf16x8 b, f32x4 c){
  return __builtin_amdgcn_mfma_f32_16x16x32_bf16(a, b, c, 0, 0, 0);
}

// ================= 256-thread (enc/dec) MLP primitives: wave tile 16x64 =================
template<int KB>
__device__ __forceinline__ void layer(const u16* sIn, int in_str, const u16* Wp,
                                      int wr, int wc, int lane, f32x4 acc[4]){
  const int row = wr*16 + (lane & 15);
  const int kg  = lane >> 4;
  #pragma unroll
  for (int kb = 0; kb < KB; ++kb){
    bf16x8 a = *(const bf16x8*)(sIn + row*in_str + kb*32 + kg*8);
    const u16* wb = Wp + (((kb*8 + wc*4)*64 + lane) << 3);
    #pragma unroll
    for (int nf = 0; nf < 4; ++nf){
      bf16x8 b = *(const bf16x8*)(wb + (nf << 9));
      acc[nf] = mfma16(a, b, acc[nf]);
    }
  }
}

__device__ __forceinline__ void hid_epi(f32x4 acc[4], const float* bias,
                                        int wr, int wc, int lane, u16* sOut){
  const int cl = lane & 15;
  const int r0 = wr*16 + (lane >> 4)*4;
  #pragma unroll
  for (int nf = 0; nf < 4; ++nf){
    int col = wc*64 + nf*16 + cl;
    float bv = bias[col];
    #pragma unroll
    for (int r = 0; r < 4; ++r){
      float v = acc[nf][r] + bv;
      sOut[(r0 + r)*H_STR + col] = f2bf(v > 0.f ? v : 0.f);
    }
  }
}

__device__ __forceinline__ void zero4(f32x4 acc[4]){
  const f32x4 vz = {0.f, 0.f, 0.f, 0.f};
  #pragma unroll
  for (int i = 0; i < 4; ++i) acc[i] = vz;
}

// ================= 512-thread edge MLP primitives: wave tile 32x32 =================
template<int KB, int STR>
__device__ __forceinline__ void layer64(const u16* sIn, const u16* Wp,
                                        int wr, int wc, int lane, f32x4 acc[2][2]){
  const int r0 = wr*32 + (lane & 15);
  const int kg = lane >> 4;
  const u16* a0p = sIn + r0*STR + kg*8;
  const u16* a1p = a0p + 16*STR;
  const u16* wb  = Wp + (((wc*2)*64 + lane) << 3);
  #pragma unroll
  for (int kb = 0; kb < KB; ++kb){
    bf16x8 a0 = *(const bf16x8*)(a0p + kb*32);
    bf16x8 a1 = *(const bf16x8*)(a1p + kb*32);
    const u16* wk = wb + kb*4096;            // kb * 8 frags * 64 lanes * 8 shorts
    bf16x8 b0 = *(const bf16x8*)(wk);
    bf16x8 b1 = *(const bf16x8*)(wk + 512);
    acc[0][0] = mfma16(a0, b0, acc[0][0]);
    acc[1][0] = mfma16(a1, b0, acc[1][0]);
    acc[0][1] = mfma16(a0, b1, acc[0][1]);
    acc[1][1] = mfma16(a1, b1, acc[1][1]);
  }
}

template<int STR>
__device__ __forceinline__ void hid_epi64(f32x4 acc[2][2], const float* bias,
                                          int wr, int wc, int lane, u16* sOut){
  const int cl = lane & 15;
  const int rq = (lane >> 4)*4;
  #pragma unroll
  for (int rf = 0; rf < 2; ++rf){
    int r0 = wr*32 + rf*16 + rq;
    #pragma unroll
    for (int nf = 0; nf < 2; ++nf){
      int col = wc*32 + nf*16 + cl;
      float bv = bias[col];
      #pragma unroll
      for (int r = 0; r < 4; ++r){
        float v = acc[rf][nf][r] + bv;
        sOut[(r0 + r)*STR + col] = f2bf(v > 0.f ? v : 0.f);
      }
    }
  }
}

__device__ __forceinline__ void zero22(f32x4 acc[2][2]){
  const f32x4 vz = {0.f, 0.f, 0.f, 0.f};
  acc[0][0] = vz; acc[0][1] = vz; acc[1][0] = vz; acc[1][1] = vz;
}

// ================= 512-thread node MLP primitives: wave tile 16x32 =================
template<int KB, int STR>
__device__ __forceinline__ void layer32(const u16* sIn, const u16* Wp,
                                        int wr, int wc, int lane, f32x4 acc[2]){
  const int r0 = wr*16 + (lane & 15);
  const int kg = lane >> 4;
  const u16* a0p = sIn + r0*STR + kg*8;
  const u16* wb  = Wp + (((wc*2)*64 + lane) << 3);
  #pragma unroll
  for (int kb = 0; kb < KB; ++kb){
    bf16x8 a0 = *(const bf16x8*)(a0p + kb*32);
    const u16* wk = wb + kb*4096;
    bf16x8 b0 = *(const bf16x8*)(wk);
    bf16x8 b1 = *(const bf16x8*)(wk + 512);
    acc[0] = mfma16(a0, b0, acc[0]);
    acc[1] = mfma16(a0, b1, acc[1]);
  }
}

template<int STR>
__device__ __forceinline__ void hid_epi32(f32x4 acc[2], const float* bias,
                                          int wr, int wc, int lane, u16* sOut){
  const int cl = lane & 15;
  const int r0 = wr*16 + (lane >> 4)*4;
  #pragma unroll
  for (int nf = 0; nf < 2; ++nf){
    int col = wc*32 + nf*16 + cl;
    float bv = bias[col];
    #pragma unroll
    for (int r = 0; r < 4; ++r){
      float v = acc[nf][r] + bv;
      sOut[(r0 + r)*STR + col] = f2bf(v > 0.f ? v : 0.f);
    }
  }
}

// -------------------- weight packing --------------------
struct PackDesc { const float* src; int K_raw, N_raw, NF, elem_off; };
struct PackArgs { PackDesc d[18]; int total; };

__global__ __launch_bounds__(256) void pack_weights(PackArgs pa, u16* dst){
  int idx = blockIdx.x*256 + threadIdx.x;
  if (idx >= pa.total) return;
  int di = 0;
  #pragma unroll
  for (int i = 1; i < 18; ++i) if (idx >= pa.d[i].elem_off) di = i;
  PackDesc dd = pa.d[di];
  int e = idx - dd.elem_off;
  int f = e >> 9, lane = (e >> 3) & 63, j = e & 7;
  int kb = f / dd.NF, nf = f % dd.NF;
  int k = kb*32 + (lane >> 4)*8 + j;
  int n = nf*16 + (lane & 15);
  float v = (k < dd.K_raw && n < dd.N_raw) ? dd.src[k*dd.N_raw + n] : 0.f;
  dst[idx] = f2bf(v);
}

// -------------------- CSR build (dst-grouped edge lists) --------------------
__global__ __launch_bounds__(256) void hist_kernel(const int* mdst, const int* cdst,
                                                   int* cnt_m, int* cnt_c){
  int i = blockIdx.x*256 + threadIdx.x;
  if (i < EM) atomicAdd(&cnt_m[mdst[i]], 1);
  else if (i < EM + EC) atomicAdd(&cnt_c[cdst[i - EM]], 1);
}

struct ScanArgs { const int *cnt_m, *cnt_c; int *start_m, *start_c, *cur_m, *cur_c; };

__global__ __launch_bounds__(256) void scan_kernel(ScanArgs a){
  const int n = NNODES;
  const int* cnt = blockIdx.x == 0 ? a.cnt_m : a.cnt_c;
  int* start     = blockIdx.x == 0 ? a.start_m : a.start_c;
  int* cur       = blockIdx.x == 0 ? a.cur_m : a.cur_c;
  __shared__ int part[256];
  __shared__ int base[257];
  int t = threadIdx.x;
  const int per = (n + 255) / 256;
  int lo = t*per, hi = min(n, lo + per);
  int s = 0;
  for (int j = lo; j < hi; ++j) s += cnt[j];
  part[t] = s;
  __syncthreads();
  if (t == 0){
    int run = 0;
    for (int i = 0; i < 256; ++i){ base[i] = run; run += part[i]; }
    base[256] = run;
  }
  __syncthreads();
  int run = base[t];
  for (int j = lo; j < hi; ++j){ start[j] = run; cur[j] = run; run += cnt[j]; }
  if (t == 255) start[n] = base[256];
}

__global__ __launch_bounds__(256) void scatter_kernel(const int* mdst, const int* cdst,
                                                      int* cur_m, int* cur_c,
                                                      int* eid_m, int* eid_c){
  int i = blockIdx.x*256 + threadIdx.x;
  if (i < EM){
    int p = atomicAdd(&cur_m[mdst[i]], 1);
    eid_m[p] = i;
  } else if (i < EM + EC){
    int e = i - EM;
    int p = atomicAdd(&cur_c[cdst[e]], 1);
    eid_c[p] = e;
  }
}

// -------------------- encoder: out = MLP(in[M,Kraw]) --------------------
struct EncArgs {
  const float* in; int Kraw;
  const u16 *Wp1, *Wp2, *Wp3;
  const float *b1, *b2, *b3;
  float* out_f32; u16* out_b16;   // out_b16 nullable
};

__global__ __launch_bounds__(256) void enc_kernel(EncArgs a){
  __shared__ u16 sA[MT*A_STR];
  __shared__ u16 sH[MT*H_STR];
  const int tid = threadIdx.x, lane = tid & 63, w = tid >> 6, wr = w & 1, wc = w >> 1;
  const int m0 = blockIdx.x * MT;
  for (int i = tid; i < MT*32; i += 256){
    int row = i >> 5, c = i & 31;
    float v = (c < a.Kraw) ? a.in[(size_t)(m0 + row)*a.Kraw + c] : 0.f;
    sA[row*A_STR + c] = f2bf(v);
  }
  __syncthreads();
  f32x4 acc[4]; zero4(acc);
  layer<1>(sA, A_STR, a.Wp1, wr, wc, lane, acc);
  hid_epi(acc, a.b1, wr, wc, lane, sH);
  __syncthreads();
  zero4(acc);
  layer<4>(sH, H_STR, a.Wp2, wr, wc, lane, acc);
  hid_epi(acc, a.b2, wr, wc, lane, sA);    // h2 reuses sA
  __syncthreads();
  zero4(acc);
  layer<4>(sA, H_STR, a.Wp3, wr, wc, lane, acc);
  const int cl = lane & 15, r0l = wr*16 + (lane >> 4)*4;
  #pragma unroll
  for (int nf = 0; nf < 4; ++nf){
    int col = wc*64 + nf*16 + cl;
    float bv = a.b3[col];
    #pragma unroll
    for (int r = 0; r < 4; ++r){
      int m = m0 + r0l + r;
      float v = acc[nf][r] + bv;
      a.out_f32[(size_t)m*LDIM + col] = v;
      if (a.out_b16) a.out_b16[(size_t)m*LDIM + col] = f2bf(v);
    }
  }
}

// -------------------- edge update: split-L1, 33.8 KB LDS -> 4 blocks/CU --------------------
// L1a over x (LDS cols 0..255), barrier, feat-bf16 overwrites cols 0..127, L1b (kb 8..11)
// accumulates into the same acc in the same kb order => numerics identical to fused L1.
struct EdgeArgs {
  const u16 *Wp1, *Wp2, *Wp3;
  const float *b1, *b2, *b3;
  const u16* x_b16;
  const int *msrc, *mdst, *csrc, *cdst;
  float *me_f32, *ce_f32;
  int mesh_blocks;
};

__global__ __launch_bounds__(512, 8) void edge_kernel(EdgeArgs a){
  __shared__ u16 sCat[MT2*X_STR];   // 33792 B: x 0..255; then feat->0..127, h1->128..255, h2->0..127; f32 delta aliases all
  const int tid = threadIdx.x, lane = tid & 63, w = tid >> 6, wr = w & 1, wc = w >> 1;
  const bool mesh = (int)blockIdx.x < a.mesh_blocks;
  const int e0 = (mesh ? (int)blockIdx.x : (int)blockIdx.x - a.mesh_blocks) * MT2;
  const int E = mesh ? EM : EC;
  const int* src = mesh ? a.msrc : a.csrc;
  const int* dst = mesh ? a.mdst : a.cdst;
  float* ff = mesh ? a.me_f32 : a.ce_f32;

  // ---- early feat f32 load (independent; latency hides under x staging) ----
  const int srow = tid >> 3, sj = tid & 7;
  int se = e0 + srow; if (se >= E) se = E - 1;
  const f32x4* fp = (const f32x4*)(ff + (size_t)se*LDIM + sj*16);
  f32x4 p0 = fp[0], p1 = fp[1], p2 = fp[2], p3 = fp[3];

  // ---- stage x[src], x[dst]: 64 rows x 32 bf16x8 chunks, coalesced ----
  #pragma unroll
  for (int i = tid; i < MT2*32; i += 512){
    int row = i >> 5, c = i & 31;
    int e = e0 + row; if (e >= E) e = E - 1;
    const u16* sp = (c < 16) ? a.x_b16 + (size_t)src[e]*LDIM + c*8
                             : a.x_b16 + (size_t)dst[e]*LDIM + (c-16)*8;
    *(bf16x8*)(sCat + row*X_STR + c*8) = *(const bf16x8*)sp;
  }
  __syncthreads();

  f32x4 acc[2][2]; zero22(acc);
  layer64<8, X_STR>(sCat, a.Wp1, wr, wc, lane, acc);     // L1a: kb 0..7 (x part)
  __syncthreads();                                        // all waves done reading x

  { // feat f32 -> bf16 -> cols 0..127 (overwrites dead x-low region)
    bf16x8 t0, t1;
    #pragma unroll
    for (int k = 0; k < 4; ++k){
      t0[k] = (short)f2bf(p0[k]); t0[k+4] = (short)f2bf(p1[k]);
      t1[k] = (short)f2bf(p2[k]); t1[k+4] = (short)f2bf(p3[k]);
    }
    *(bf16x8*)(sCat + srow*X_STR + sj*16) = t0;
    *(bf16x8*)(sCat + srow*X_STR + sj*16 + 8) = t1;
  }
  __syncthreads();

  layer64<4, X_STR>(sCat, a.Wp1 + 8*4096, wr, wc, lane, acc);  // L1b: kb 8..11 (feat part)
  hid_epi64<X_STR>(acc, a.b1, wr, wc, lane, sCat + 128);       // h1 -> cols 128..255 (disjoint from feat reads)
  __syncthreads();
  zero22(acc);
  layer64<4, X_STR>(sCat + 128, a.Wp2, wr, wc, lane, acc);
  hid_epi64<X_STR>(acc, a.b2, wr, wc, lane, sCat);             // h2 -> cols 0..127 (disjoint from h1 reads)
  __syncthreads();
  zero22(acc);
  layer64<4, X_STR>(sCat, a.Wp3, wr, wc, lane, acc);
  __syncthreads();                                             // all h2 reads done; delta may overwrite

  // ---- delta (acc + b3) -> f32 LDS, then residual RMW from registered f32 ----
  float* dd = (float*)sCat;                                    // [64][D_STR] f32 = 33792 B exactly
  {
    const int cl = lane & 15, rq = (lane >> 4)*4;
    #pragma unroll
    for (int rf = 0; rf < 2; ++rf){
      #pragma unroll
      for (int nf = 0; nf < 2; ++nf){
        int col = wc*32 + nf*16 + cl;
        float bv = a.b3[col];
        #pragma unroll
        for (int r = 0; r < 4; ++r)
          dd[(wr*32 + rf*16 + rq + r)*D_STR + col] = acc[rf][nf][r] + bv;
      }
    }
  }
  __syncthreads();
  if (e0 + srow < E){
    float* op = ff + (size_t)(e0 + srow)*LDIM + sj*16;
    const f32x4* dp = (const f32x4*)(dd + srow*D_STR + sj*16);
    f32x4 n0 = p0 + dp[0], n1 = p1 + dp[1], n2 = p2 + dp[2], n3 = p3 + dp[3];
    ((f32x4*)op)[0] = n0; ((f32x4*)op)[1] = n1; ((f32x4*)op)[2] = n2; ((f32x4*)op)[3] = n3;
  }
}

// -------------------- node update: MT=32 rows, 512 threads, 625 blocks --------------------
struct NodeArgs {
  const u16 *Wp1, *Wp2, *Wp3;
  const float *b1, *b2, *b3;
  const u16* x_b16_in;
  const float *me_f32, *ce_f32;
  const int *start_m, *eid_m, *start_c, *eid_c;
  float* x_f32; u16* x_b16_out;
};

__global__ __launch_bounds__(512, 8) void node_kernel(NodeArgs a){
  __shared__ u16 sA[MT*A_STR];   // concat: x 0..127 | agg_m 128..255 | agg_c 256..383; h1 aliases 256.., h2 aliases 0..
  const int tid = threadIdx.x, lane = tid & 63, w = tid >> 6, wr = w & 1, wc = w >> 1;
  const int n0 = blockIdx.x * MT;        // 20000/32 = 625 blocks exact, no bounds checks

  // stage x (bf16 mirror): 32 rows x 16 chunks = 512, one per thread
  {
    int row = tid >> 4, ch = tid & 15;
    *(bf16x8*)(sA + row*A_STR + ch*8) =
        *(const bf16x8*)(a.x_b16_in + (size_t)(n0+row)*LDIM + ch*8);
  }
  // CSR gather-mean: 16 threads per node, 8 cols each
  {
    const int r = tid >> 4, c0 = (tid & 15) * 8;
    const int n = n0 + r;
    // mesh -> cols 128..255
    {
      int s = a.start_m[n], e = a.start_m[n+1];
      f32x4 a0{0,0,0,0}, a1{0,0,0,0};
      for (int j = s; j < e; ++j){
        const f32x4* p = (const f32x4*)(a.me_f32 + (size_t)a.eid_m[j]*LDIM + c0);
        a0 += p[0]; a1 += p[1];
      }
      float inv = 1.f / fmaxf((float)(e - s), 1.f);
      bf16x8 t;
      #pragma unroll
      for (int k = 0; k < 4; ++k){ t[k] = (short)f2bf(a0[k]*inv); t[k+4] = (short)f2bf(a1[k]*inv); }
      *(bf16x8*)(sA + r*A_STR + 128 + c0) = t;
    }
    // contact -> cols 256..383
    {
      int s = a.start_c[n], e = a.start_c[n+1];
      f32x4 a0{0,0,0,0}, a1{0,0,0,0};
      for (int j = s; j < e; ++j){
        const f32x4* p = (const f32x4*)(a.ce_f32 + (size_t)a.eid_c[j]*LDIM + c0);
        a0 += p[0]; a1 += p[1];
      }
      float inv = 1.f / fmaxf((float)(e - s), 1.f);
      bf16x8 t;
      #pragma unroll
      for (int k = 0; k < 4; ++k){ t[k] = (short)f2bf(a0[k]*inv); t[k+4] = (short)f2bf(a1[k]*inv); }
      *(bf16x8*)(sA + r*A_STR + 256 + c0) = t;
    }
  }
  __syncthreads();

  f32x4 acc[2]; acc[0] = f32x4{0,0,0,0}; acc[1] = f32x4{0,0,0,0};
  layer32<12, A_STR>(sA, a.Wp1, wr, wc, lane, acc);
  __syncthreads();                                   // all waves done reading concat
  hid_epi32<A_STR>(acc, a.b1, wr, wc, lane, sA + 256);   // h1 -> cols 256..383
  __syncthreads();
  acc[0] = f32x4{0,0,0,0}; acc[1] = f32x4{0,0,0,0};
  layer32<4, A_STR>(sA + 256, a.Wp2, wr, wc, lane, acc);
  hid_epi32<A_STR>(acc, a.b2, wr, wc, lane, sA);         // h2 -> cols 0..127 (disjoint)
  __syncthreads();
  acc[0] = f32x4{0,0,0,0}; acc[1] = f32x4{0,0,0,0};
  layer32<4, A_STR>(sA, a.Wp3, wr, wc, lane, acc);

  const int cl = lane & 15, rq = (lane >> 4)*4;
  #pragma unroll
  for (int r = 0; r < 4; ++r){
    int n = n0 + wr*16 + rq + r;
    #pragma unroll
    for (int nf = 0; nf < 2; ++nf){
      int col = wc*32 + nf*16 + cl;
      float nv = a.x_f32[(size_t)n*LDIM + col] + acc[nf][r] + a.b3[col];
      a.x_f32[(size_t)n*LDIM + col] = nv;
      a.x_b16_out[(size_t)n*LDIM + col] = f2bf(nv);
    }
  }
}

// -------------------- decoder: out[N,3] --------------------
struct DecArgs {
  const u16 *Wp1, *Wp2, *Wp3;
  const float *b1, *b2, *b3;
  const u16* x_b16; float* out;
};

__global__ __launch_bounds__(256) void dec_kernel(DecArgs a){
  __shared__ u16 sA[MT*A_STR];
  __shared__ u16 sH[MT*H_STR];
  const int tid = threadIdx.x, lane = tid & 63, w = tid >> 6, wr = w & 1, wc = w >> 1;
  const int n0 = blockIdx.x * MT;
  for (int i = tid; i < MT*16; i += 256){
    int row = i >> 4, ch = i & 15;
    *(bf16x8*)(sA + row*H_STR + ch*8) = *(const bf16x8*)(a.x_b16 + (size_t)(n0+row)*LDIM + ch*8);
  }
  __syncthreads();
  f32x4 acc[4]; zero4(acc);
  layer<4>(sA, H_STR, a.Wp1, wr, wc, lane, acc);
  hid_epi(acc, a.b1, wr, wc, lane, sH);
  __syncthreads();
  zero4(acc);
  layer<4>(sH, H_STR, a.Wp2, wr, wc, lane, acc);
  hid_epi(acc, a.b2, wr, wc, lane, sA);
  __syncthreads();
  if (wc == 0){
    f32x4 a3 = {0.f, 0.f, 0.f, 0.f};
    const int row = wr*16 + (lane & 15), kg = lane >> 4;
    #pragma unroll
    for (int kb = 0; kb < 4; ++kb){
      bf16x8 av = *(const bf16x8*)(sA + row*H_STR + kb*32 + kg*8);
      bf16x8 bv = *(const bf16x8*)(a.Wp3 + ((kb*64 + lane) << 3));
      a3 = mfma16(av, bv, a3);
    }
    const int cl = lane & 15, r0l = wr*16 + (lane >> 4)*4;
    if (cl < 3){
      #pragma unroll
      for (int r = 0; r < 4; ++r)
        a.out[(size_t)(n0 + r0l + r)*3 + cl] = a3[r] + a.b3[cl];
    }
  }
}

// -------------------- host --------------------
extern "C" void kernel_launch(void* const* d_in, const int* in_sizes, int n_in,
                              void* d_out, int out_size, void* d_ws, size_t ws_size,
                              hipStream_t stream){
  auto F = [&](int i){ return (const float*)d_in[i]; };
  const float* node_x   = F(0);
  const float* mesh_attr = F(1);
  const float* cont_attr = F(2);
  const int* mei = (const int*)d_in[39];
  const int* cei = (const int*)d_in[40];
  const int *msrc = mei, *mdst = mei + EM, *csrc = cei, *cdst = cei + EC;

  char* ws = (char*)d_ws;
  size_t off = 0;
  auto take = [&](size_t b)->void*{ void* p = ws + off; off += (b + 255) & ~(size_t)255; return p; };
  float* x_f32  = (float*)take((size_t)NNODES*LDIM*4);
  u16*   x_b16  = (u16*)  take((size_t)NNODES*LDIM*2);
  float* me_f32 = (float*)take((size_t)EM*LDIM*4);
  float* ce_f32 = (float*)take((size_t)EC*LDIM*4);
  u16*   wpack  = (u16*)  take((size_t)309248*2);
  int* cnt_m   = (int*)take((size_t)NNODES*4);      // cnt_m/cnt_c adjacent: one memset
  int* cnt_c   = (int*)take((size_t)NNODES*4);
  int* start_m = (int*)take((size_t)(NNODES+1)*4);
  int* start_c = (int*)take((size_t)(NNODES+1)*4);
  int* cur_m   = (int*)take((size_t)NNODES*4);
  int* cur_c   = (int*)take((size_t)NNODES*4);
  int* eid_m   = (int*)take((size_t)EM*4);
  int* eid_c   = (int*)take((size_t)EC*4);

  // {d_in idx, K_raw, N_raw, K_pad, N_pad}
  static const int tbl[18][5] = {
    {3,12,128,32,128},{5,128,128,128,128},{7,128,128,128,128},      // ne
    {9,7,128,32,128},{11,128,128,128,128},{13,128,128,128,128},     // me
    {15,4,128,32,128},{17,128,128,128,128},{19,128,128,128,128},    // ce
    {21,384,128,384,128},{23,128,128,128,128},{25,128,128,128,128}, // pe
    {27,384,128,384,128},{29,128,128,128,128},{31,128,128,128,128}, // pn
    {33,128,128,128,128},{35,128,128,128,128},{37,128,3,128,16}};   // de
  PackArgs pa; int eo = 0; int offs[18];
  for (int i = 0; i < 18; ++i){
    offs[i] = eo;
    pa.d[i].src = F(tbl[i][0]);
    pa.d[i].K_raw = tbl[i][1];
    pa.d[i].N_raw = tbl[i][2];
    pa.d[i].NF = tbl[i][4] / 16;
    pa.d[i].elem_off = eo;
    eo += tbl[i][3] * tbl[i][4];
  }
  pa.total = eo;  // 309248
  pack_weights<<<dim3(eo/256), dim3(256), 0, stream>>>(pa, wpack);

  // CSR build (per call; edge indices are constant inputs)
  size_t cnt_span = ((char*)cnt_c - (char*)cnt_m) + (size_t)NNODES*4;
  hipMemsetAsync(cnt_m, 0, cnt_span, stream);
  hist_kernel<<<dim3((EM + EC + 255)/256), dim3(256), 0, stream>>>(mdst, cdst, cnt_m, cnt_c);
  ScanArgs sa{cnt_m, cnt_c, start_m, start_c, cur_m, cur_c};
  scan_kernel<<<dim3(2), dim3(256), 0, stream>>>(sa);
  scatter_kernel<<<dim3((EM + EC + 255)/256), dim3(256), 0, stream>>>(mdst, cdst, cur_m, cur_c, eid_m, eid_c);

  EncArgs en{node_x, 12, wpack+offs[0], wpack+offs[1], wpack+offs[2], F(4), F(6), F(8), x_f32, x_b16};
  enc_kernel<<<dim3(NNODES/MT), dim3(256), 0, stream>>>(en);
  EncArgs em{mesh_attr, 7, wpack+offs[3], wpack+offs[4], wpack+offs[5], F(10), F(12), F(14), me_f32, nullptr};
  enc_kernel<<<dim3(EM/MT), dim3(256), 0, stream>>>(em);
  EncArgs ec{cont_attr, 4, wpack+offs[6], wpack+offs[7], wpack+offs[8], F(16), F(18), F(20), ce_f32, nullptr};
  enc_kernel<<<dim3(EC/MT), dim3(256), 0, stream>>>(ec);

  EdgeArgs ea;
  ea.Wp1 = wpack+offs[9]; ea.Wp2 = wpack+offs[10]; ea.Wp3 = wpack+offs[11];
  ea.b1 = F(22); ea.b2 = F(24); ea.b3 = F(26);
  ea.x_b16 = x_b16;
  ea.msrc = msrc; ea.mdst = mdst; ea.csrc = csrc; ea.cdst = cdst;
  ea.me_f32 = me_f32; ea.ce_f32 = ce_f32;
  ea.mesh_blocks = EM/MT2;                                  // 1875

  NodeArgs na;
  na.Wp1 = wpack+offs[12]; na.Wp2 = wpack+offs[13]; na.Wp3 = wpack+offs[14];
  na.b1 = F(28); na.b2 = F(30); na.b3 = F(32);
  na.x_b16_in = x_b16;
  na.me_f32 = me_f32; na.ce_f32 = ce_f32;
  na.start_m = start_m; na.eid_m = eid_m; na.start_c = start_c; na.eid_c = eid_c;
  na.x_f32 = x_f32; na.x_b16_out = x_b16;

  const int edge_blocks = EM/MT2 + (EC + MT2 - 1)/MT2;      // 1875 + 313
  const int node_blocks = NNODES/MT;                        // 625
  for (int s = 0; s < 10; ++s){
    edge_kernel<<<dim3(edge_blocks), dim3(512), 0, stream>>>(ea);
    node_kernel<<<dim3(node_blocks), dim3(512), 0, stream>>>(na);
  }

  DecArgs da{wpack+offs[15], wpack+offs[16], wpack+offs[17], F(34), F(36), F(38), x_b16, (float*)d_out};
  dec_kernel<<<dim3(NNODES/MT), dim3(256), 0, stream>>>(da);
}

// Round 12
// 1150.466 us; speedup vs baseline: 1.0885x; 1.0885x over previous
//
#include <hip/hip_runtime.h>
#include <stdint.h>

typedef unsigned short u16;
typedef __attribute__((ext_vector_type(8))) short bf16x8;   // 8 bf16 = 4 VGPRs (MFMA A/B frag)
typedef __attribute__((ext_vector_type(4))) float f32x4;    // MFMA C/D frag

#define NNODES 20000
#define EM 120000
#define EC 20000
#define LDIM 128
#define MT 32          // rows per block (enc/dec/node kernels)
#define MT2 64         // rows per block (edge kernel, 512 threads)
#define A_STR 392      // concat LDS stride in shorts (384+8 pad -> 4-bank shift/row)
#define H_STR 136      // 128+8 pad
#define D_STR 132      // f32 delta stride (128+4 pad)

__device__ __forceinline__ u16 f2bf(float f){
  uint32_t b = __float_as_uint(f);
  b += 0x7FFF + ((b >> 16) & 1);          // RNE
  return (u16)(b >> 16);
}

__device__ __forceinline__ f32x4 mfma16(bf16x8 a, bf16x8 b, f32x4 c){
  return __builtin_amdgcn_mfma_f32_16x16x32_bf16(a, b, c, 0, 0, 0);
}

// ================= 256-thread (enc/dec) MLP primitives: wave tile 16x64 =================
template<int KB>
__device__ __forceinline__ void layer(const u16* sIn, int in_str, const u16* Wp,
                                      int wr, int wc, int lane, f32x4 acc[4]){
  const int row = wr*16 + (lane & 15);
  const int kg  = lane >> 4;
  #pragma unroll
  for (int kb = 0; kb < KB; ++kb){
    bf16x8 a = *(const bf16x8*)(sIn + row*in_str + kb*32 + kg*8);
    const u16* wb = Wp + (((kb*8 + wc*4)*64 + lane) << 3);
    #pragma unroll
    for (int nf = 0; nf < 4; ++nf){
      bf16x8 b = *(const bf16x8*)(wb + (nf << 9));
      acc[nf] = mfma16(a, b, acc[nf]);
    }
  }
}

__device__ __forceinline__ void hid_epi(f32x4 acc[4], const float* bias,
                                        int wr, int wc, int lane, u16* sOut){
  const int cl = lane & 15;
  const int r0 = wr*16 + (lane >> 4)*4;
  #pragma unroll
  for (int nf = 0; nf < 4; ++nf){
    int col = wc*64 + nf*16 + cl;
    float bv = bias[col];
    #pragma unroll
    for (int r = 0; r < 4; ++r){
      float v = acc[nf][r] + bv;
      sOut[(r0 + r)*H_STR + col] = f2bf(v > 0.f ? v : 0.f);
    }
  }
}

__device__ __forceinline__ void zero4(f32x4 acc[4]){
  const f32x4 vz = {0.f, 0.f, 0.f, 0.f};
  #pragma unroll
  for (int i = 0; i < 4; ++i) acc[i] = vz;
}

// ================= 512-thread edge MLP primitives: wave tile 32x32 =================
template<int KB, int STR>
__device__ __forceinline__ void layer64(const u16* sIn, const u16* Wp,
                                        int wr, int wc, int lane, f32x4 acc[2][2]){
  const int r0 = wr*32 + (lane & 15);
  const int kg = lane >> 4;
  const u16* a0p = sIn + r0*STR + kg*8;
  const u16* a1p = a0p + 16*STR;
  const u16* wb  = Wp + (((wc*2)*64 + lane) << 3);
  #pragma unroll
  for (int kb = 0; kb < KB; ++kb){
    bf16x8 a0 = *(const bf16x8*)(a0p + kb*32);
    bf16x8 a1 = *(const bf16x8*)(a1p + kb*32);
    const u16* wk = wb + kb*4096;            // kb * 8 frags * 64 lanes * 8 shorts
    bf16x8 b0 = *(const bf16x8*)(wk);
    bf16x8 b1 = *(const bf16x8*)(wk + 512);
    acc[0][0] = mfma16(a0, b0, acc[0][0]);
    acc[1][0] = mfma16(a1, b0, acc[1][0]);
    acc[0][1] = mfma16(a0, b1, acc[0][1]);
    acc[1][1] = mfma16(a1, b1, acc[1][1]);
  }
}

template<int STR>
__device__ __forceinline__ void hid_epi64(f32x4 acc[2][2], const float* bias,
                                          int wr, int wc, int lane, u16* sOut){
  const int cl = lane & 15;
  const int rq = (lane >> 4)*4;
  #pragma unroll
  for (int rf = 0; rf < 2; ++rf){
    int r0 = wr*32 + rf*16 + rq;
    #pragma unroll
    for (int nf = 0; nf < 2; ++nf){
      int col = wc*32 + nf*16 + cl;
      float bv = bias[col];
      #pragma unroll
      for (int r = 0; r < 4; ++r){
        float v = acc[rf][nf][r] + bv;
        sOut[(r0 + r)*STR + col] = f2bf(v > 0.f ? v : 0.f);
      }
    }
  }
}

__device__ __forceinline__ void zero22(f32x4 acc[2][2]){
  const f32x4 vz = {0.f, 0.f, 0.f, 0.f};
  acc[0][0] = vz; acc[0][1] = vz; acc[1][0] = vz; acc[1][1] = vz;
}

// ================= 512-thread node MLP primitives: wave tile 16x32 =================
template<int KB, int STR>
__device__ __forceinline__ void layer32(const u16* sIn, const u16* Wp,
                                        int wr, int wc, int lane, f32x4 acc[2]){
  const int r0 = wr*16 + (lane & 15);
  const int kg = lane >> 4;
  const u16* a0p = sIn + r0*STR + kg*8;
  const u16* wb  = Wp + (((wc*2)*64 + lane) << 3);
  #pragma unroll
  for (int kb = 0; kb < KB; ++kb){
    bf16x8 a0 = *(const bf16x8*)(a0p + kb*32);
    const u16* wk = wb + kb*4096;
    bf16x8 b0 = *(const bf16x8*)(wk);
    bf16x8 b1 = *(const bf16x8*)(wk + 512);
    acc[0] = mfma16(a0, b0, acc[0]);
    acc[1] = mfma16(a0, b1, acc[1]);
  }
}

template<int STR>
__device__ __forceinline__ void hid_epi32(f32x4 acc[2], const float* bias,
                                          int wr, int wc, int lane, u16* sOut){
  const int cl = lane & 15;
  const int r0 = wr*16 + (lane >> 4)*4;
  #pragma unroll
  for (int nf = 0; nf < 2; ++nf){
    int col = wc*32 + nf*16 + cl;
    float bv = bias[col];
    #pragma unroll
    for (int r = 0; r < 4; ++r){
      float v = acc[nf][r] + bv;
      sOut[(r0 + r)*STR + col] = f2bf(v > 0.f ? v : 0.f);
    }
  }
}

// -------------------- weight packing --------------------
struct PackDesc { const float* src; int K_raw, N_raw, NF, elem_off; };
struct PackArgs { PackDesc d[18]; int total; };

__global__ __launch_bounds__(256) void pack_weights(PackArgs pa, u16* dst){
  int idx = blockIdx.x*256 + threadIdx.x;
  if (idx >= pa.total) return;
  int di = 0;
  #pragma unroll
  for (int i = 1; i < 18; ++i) if (idx >= pa.d[i].elem_off) di = i;
  PackDesc dd = pa.d[di];
  int e = idx - dd.elem_off;
  int f = e >> 9, lane = (e >> 3) & 63, j = e & 7;
  int kb = f / dd.NF, nf = f % dd.NF;
  int k = kb*32 + (lane >> 4)*8 + j;
  int n = nf*16 + (lane & 15);
  float v = (k < dd.K_raw && n < dd.N_raw) ? dd.src[k*dd.N_raw + n] : 0.f;
  dst[idx] = f2bf(v);
}

// -------------------- CSR build (dst-grouped edge order) --------------------
__global__ __launch_bounds__(256) void hist_kernel(const int* mdst, const int* cdst,
                                                   int* cnt_m, int* cnt_c){
  int i = blockIdx.x*256 + threadIdx.x;
  if (i < EM) atomicAdd(&cnt_m[mdst[i]], 1);
  else if (i < EM + EC) atomicAdd(&cnt_c[cdst[i - EM]], 1);
}

struct ScanArgs { const int *cnt_m, *cnt_c; int *start_m, *start_c, *cur_m, *cur_c; };

__global__ __launch_bounds__(256) void scan_kernel(ScanArgs a){
  const int n = NNODES;
  const int* cnt = blockIdx.x == 0 ? a.cnt_m : a.cnt_c;
  int* start     = blockIdx.x == 0 ? a.start_m : a.start_c;
  int* cur       = blockIdx.x == 0 ? a.cur_m : a.cur_c;
  __shared__ int part[256];
  __shared__ int base[257];
  int t = threadIdx.x;
  const int per = (n + 255) / 256;
  int lo = t*per, hi = min(n, lo + per);
  int s = 0;
  for (int j = lo; j < hi; ++j) s += cnt[j];
  part[t] = s;
  __syncthreads();
  if (t == 0){
    int run = 0;
    for (int i = 0; i < 256; ++i){ base[i] = run; run += part[i]; }
    base[256] = run;
  }
  __syncthreads();
  int run = base[t];
  for (int j = lo; j < hi; ++j){ start[j] = run; cur[j] = run; run += cnt[j]; }
  if (t == 255) start[n] = base[256];
}

// pos[i] = CSR slot of original edge i
__global__ __launch_bounds__(256) void scatter_kernel(const int* mdst, const int* cdst,
                                                      int* cur_m, int* cur_c,
                                                      int* pos_m, int* pos_c){
  int i = blockIdx.x*256 + threadIdx.x;
  if (i < EM){
    int p = atomicAdd(&cur_m[mdst[i]], 1);
    pos_m[i] = p;
  } else if (i < EM + EC){
    int e = i - EM;
    int p = atomicAdd(&cur_c[cdst[e]], 1);
    pos_c[e] = p;
  }
}

// sp/dp[slot] = src/dst of the edge stored at that CSR slot (contiguous for edge kernel)
__global__ __launch_bounds__(256) void permsd_kernel(const int* msrc, const int* mdst, const int* pos_m,
                                                     const int* csrc, const int* cdst, const int* pos_c,
                                                     int* sp_m, int* dp_m, int* sp_c, int* dp_c){
  int i = blockIdx.x*256 + threadIdx.x;
  if (i < EM){
    int p = pos_m[i];
    sp_m[p] = msrc[i]; dp_m[p] = mdst[i];
  } else if (i < EM + EC){
    int e = i - EM;
    int p = pos_c[e];
    sp_c[p] = csrc[e]; dp_c[p] = cdst[e];
  }
}

// -------------------- encoder: out[perm[m]] = MLP(in[m]) --------------------
struct EncArgs {
  const float* in; int Kraw;
  const u16 *Wp1, *Wp2, *Wp3;
  const float *b1, *b2, *b3;
  float* out_f32; u16* out_b16;   // out_b16 nullable
  const int* perm;                // nullable: out row = perm ? perm[m] : m
};

__global__ __launch_bounds__(256) void enc_kernel(EncArgs a){
  __shared__ u16 sA[MT*A_STR];
  __shared__ u16 sH[MT*H_STR];
  const int tid = threadIdx.x, lane = tid & 63, w = tid >> 6, wr = w & 1, wc = w >> 1;
  const int m0 = blockIdx.x * MT;
  for (int i = tid; i < MT*32; i += 256){
    int row = i >> 5, c = i & 31;
    float v = (c < a.Kraw) ? a.in[(size_t)(m0 + row)*a.Kraw + c] : 0.f;
    sA[row*A_STR + c] = f2bf(v);
  }
  __syncthreads();
  f32x4 acc[4]; zero4(acc);
  layer<1>(sA, A_STR, a.Wp1, wr, wc, lane, acc);
  hid_epi(acc, a.b1, wr, wc, lane, sH);
  __syncthreads();
  zero4(acc);
  layer<4>(sH, H_STR, a.Wp2, wr, wc, lane, acc);
  hid_epi(acc, a.b2, wr, wc, lane, sA);    // h2 reuses sA
  __syncthreads();
  zero4(acc);
  layer<4>(sA, H_STR, a.Wp3, wr, wc, lane, acc);
  const int cl = lane & 15, r0l = wr*16 + (lane >> 4)*4;
  #pragma unroll
  for (int nf = 0; nf < 4; ++nf){
    int col = wc*64 + nf*16 + cl;
    float bv = a.b3[col];
    #pragma unroll
    for (int r = 0; r < 4; ++r){
      int m = m0 + r0l + r;
      int om = a.perm ? a.perm[m] : m;
      float v = acc[nf][r] + bv;
      a.out_f32[(size_t)om*LDIM + col] = v;
      if (a.out_b16) a.out_b16[(size_t)om*LDIM + col] = f2bf(v);
    }
  }
}

// -------------------- edge update (R7-benched structure; CSR-slot storage) --------------------
// Edge features stored in CSR(dst-sorted) slot order; sp/dp give src/dst per slot (contiguous).
struct EdgeArgs {
  const u16 *Wp1, *Wp2, *Wp3;
  const float *b1, *b2, *b3;
  const u16* x_b16;
  const int *sp_m, *dp_m, *sp_c, *dp_c;
  float *me_f32, *ce_f32;
  int mesh_blocks;
};

__global__ __launch_bounds__(512, 6) void edge_kernel(EdgeArgs a){
  __shared__ u16 sCat[MT2*A_STR];   // 49.1 KB: concat; h1->cols 256..383, h2->cols 0..127; f32 delta aliases base
  const int tid = threadIdx.x, lane = tid & 63, w = tid >> 6, wr = w & 1, wc = w >> 1;
  const bool mesh = (int)blockIdx.x < a.mesh_blocks;
  const int e0 = (mesh ? (int)blockIdx.x : (int)blockIdx.x - a.mesh_blocks) * MT2;
  const int E = mesh ? EM : EC;
  const int* sp = mesh ? a.sp_m : a.sp_c;
  const int* dp = mesh ? a.dp_m : a.dp_c;
  float* ff = mesh ? a.me_f32 : a.ce_f32;

  // ---- stage x[src], x[dst]: 64 rows x 32 bf16x8 chunks, coalesced ----
  #pragma unroll
  for (int i = tid; i < MT2*32; i += 512){
    int row = i >> 5, c = i & 31;
    int e = e0 + row; if (e >= E) e = E - 1;
    const u16* xp = (c < 16) ? a.x_b16 + (size_t)sp[e]*LDIM + c*8
                             : a.x_b16 + (size_t)dp[e]*LDIM + (c-16)*8;
    *(bf16x8*)(sCat + row*A_STR + c*8) = *(const bf16x8*)xp;
  }
  // ---- stage feat (f32->bf16), keep f32 in regs for epilogue ----
  const int srow = tid >> 3, sj = tid & 7;
  int se = e0 + srow; if (se >= E) se = E - 1;
  const f32x4* fp = (const f32x4*)(ff + (size_t)se*LDIM + sj*16);
  f32x4 p0 = fp[0], p1 = fp[1], p2 = fp[2], p3 = fp[3];
  {
    bf16x8 t0, t1;
    #pragma unroll
    for (int k = 0; k < 4; ++k){
      t0[k] = (short)f2bf(p0[k]); t0[k+4] = (short)f2bf(p1[k]);
      t1[k] = (short)f2bf(p2[k]); t1[k+4] = (short)f2bf(p3[k]);
    }
    *(bf16x8*)(sCat + srow*A_STR + 256 + sj*16) = t0;
    *(bf16x8*)(sCat + srow*A_STR + 256 + sj*16 + 8) = t1;
  }
  __syncthreads();

  f32x4 acc[2][2]; zero22(acc);
  layer64<12, A_STR>(sCat, a.Wp1, wr, wc, lane, acc);
  __syncthreads();                                   // all waves done reading concat
  hid_epi64<A_STR>(acc, a.b1, wr, wc, lane, sCat + 256);   // h1 -> cols 256..383
  __syncthreads();
  zero22(acc);
  layer64<4, A_STR>(sCat + 256, a.Wp2, wr, wc, lane, acc);
  hid_epi64<A_STR>(acc, a.b2, wr, wc, lane, sCat);         // h2 -> cols 0..127 (disjoint)
  __syncthreads();
  zero22(acc);
  layer64<4, A_STR>(sCat, a.Wp3, wr, wc, lane, acc);
  __syncthreads();                                   // all h2 reads done; delta may overwrite

  // ---- delta (acc + b3) -> f32 LDS, then residual RMW from registered f32 ----
  float* dd = (float*)sCat;                          // [64][D_STR] f32 = 33.8 KB
  {
    const int cl = lane & 15, rq = (lane >> 4)*4;
    #pragma unroll
    for (int rf = 0; rf < 2; ++rf){
      #pragma unroll
      for (int nf = 0; nf < 2; ++nf){
        int col = wc*32 + nf*16 + cl;
        float bv = a.b3[col];
        #pragma unroll
        for (int r = 0; r < 4; ++r)
          dd[(wr*32 + rf*16 + rq + r)*D_STR + col] = acc[rf][nf][r] + bv;
      }
    }
  }
  __syncthreads();
  if (e0 + srow < E){
    float* op = ff + (size_t)(e0 + srow)*LDIM + sj*16;
    const f32x4* dp_ = (const f32x4*)(dd + srow*D_STR + sj*16);
    f32x4 n0 = p0 + dp_[0], n1 = p1 + dp_[1], n2 = p2 + dp_[2], n3 = p3 + dp_[3];
    ((f32x4*)op)[0] = n0; ((f32x4*)op)[1] = n1; ((f32x4*)op)[2] = n2; ((f32x4*)op)[3] = n3;
  }
}

// -------------------- node update: contiguous CSR gather + MLP --------------------
struct NodeArgs {
  const u16 *Wp1, *Wp2, *Wp3;
  const float *b1, *b2, *b3;
  const u16* x_b16_in;
  const float *me_f32, *ce_f32;
  const int *start_m, *start_c;
  float* x_f32; u16* x_b16_out;
};

__global__ __launch_bounds__(512, 6) void node_kernel(NodeArgs a){
  __shared__ u16 sA[MT*A_STR];   // concat: x 0..127 | agg_m 128..255 | agg_c 256..383; h1 aliases 256.., h2 aliases 0..
  const int tid = threadIdx.x, lane = tid & 63, w = tid >> 6, wr = w & 1, wc = w >> 1;
  const int n0 = blockIdx.x * MT;        // 20000/32 = 625 blocks exact, no bounds checks

  // stage x (bf16 mirror): 32 rows x 16 chunks = 512, one per thread
  {
    int row = tid >> 4, ch = tid & 15;
    *(bf16x8*)(sA + row*A_STR + ch*8) =
        *(const bf16x8*)(a.x_b16_in + (size_t)(n0+row)*LDIM + ch*8);
  }
  // CSR gather-mean, CONTIGUOUS rows: 16 threads per node, 8 cols each
  {
    const int r = tid >> 4, c0 = (tid & 15) * 8;
    const int n = n0 + r;
    // mesh -> cols 128..255
    {
      int s = a.start_m[n], e = a.start_m[n+1];
      f32x4 a0{0,0,0,0}, a1{0,0,0,0};
      for (int j = s; j < e; ++j){
        const f32x4* p = (const f32x4*)(a.me_f32 + (size_t)j*LDIM + c0);
        a0 += p[0]; a1 += p[1];
      }
      float inv = 1.f / fmaxf((float)(e - s), 1.f);
      bf16x8 t;
      #pragma unroll
      for (int k = 0; k < 4; ++k){ t[k] = (short)f2bf(a0[k]*inv); t[k+4] = (short)f2bf(a1[k]*inv); }
      *(bf16x8*)(sA + r*A_STR + 128 + c0) = t;
    }
    // contact -> cols 256..383
    {
      int s = a.start_c[n], e = a.start_c[n+1];
      f32x4 a0{0,0,0,0}, a1{0,0,0,0};
      for (int j = s; j < e; ++j){
        const f32x4* p = (const f32x4*)(a.ce_f32 + (size_t)j*LDIM + c0);
        a0 += p[0]; a1 += p[1];
      }
      float inv = 1.f / fmaxf((float)(e - s), 1.f);
      bf16x8 t;
      #pragma unroll
      for (int k = 0; k < 4; ++k){ t[k] = (short)f2bf(a0[k]*inv); t[k+4] = (short)f2bf(a1[k]*inv); }
      *(bf16x8*)(sA + r*A_STR + 256 + c0) = t;
    }
  }
  __syncthreads();

  f32x4 acc[2]; acc[0] = f32x4{0,0,0,0}; acc[1] = f32x4{0,0,0,0};
  layer32<12, A_STR>(sA, a.Wp1, wr, wc, lane, acc);
  __syncthreads();                                   // all waves done reading concat
  hid_epi32<A_STR>(acc, a.b1, wr, wc, lane, sA + 256);   // h1 -> cols 256..383
  __syncthreads();
  acc[0] = f32x4{0,0,0,0}; acc[1] = f32x4{0,0,0,0};
  layer32<4, A_STR>(sA + 256, a.Wp2, wr, wc, lane, acc);
  hid_epi32<A_STR>(acc, a.b2, wr, wc, lane, sA);         // h2 -> cols 0..127 (disjoint)
  __syncthreads();
  acc[0] = f32x4{0,0,0,0}; acc[1] = f32x4{0,0,0,0};
  layer32<4, A_STR>(sA, a.Wp3, wr, wc, lane, acc);

  const int cl = lane & 15, rq = (lane >> 4)*4;
  #pragma unroll
  for (int r = 0; r < 4; ++r){
    int n = n0 + wr*16 + rq + r;
    #pragma unroll
    for (int nf = 0; nf < 2; ++nf){
      int col = wc*32 + nf*16 + cl;
      float nv = a.x_f32[(size_t)n*LDIM + col] + acc[nf][r] + a.b3[col];
      a.x_f32[(size_t)n*LDIM + col] = nv;
      a.x_b16_out[(size_t)n*LDIM + col] = f2bf(nv);
    }
  }
}

// -------------------- decoder: out[N,3] --------------------
struct DecArgs {
  const u16 *Wp1, *Wp2, *Wp3;
  const float *b1, *b2, *b3;
  const u16* x_b16; float* out;
};

__global__ __launch_bounds__(256) void dec_kernel(DecArgs a){
  __shared__ u16 sA[MT*A_STR];
  __shared__ u16 sH[MT*H_STR];
  const int tid = threadIdx.x, lane = tid & 63, w = tid >> 6, wr = w & 1, wc = w >> 1;
  const int n0 = blockIdx.x * MT;
  for (int i = tid; i < MT*16; i += 256){
    int row = i >> 4, ch = i & 15;
    *(bf16x8*)(sA + row*H_STR + ch*8) = *(const bf16x8*)(a.x_b16 + (size_t)(n0+row)*LDIM + ch*8);
  }
  __syncthreads();
  f32x4 acc[4]; zero4(acc);
  layer<4>(sA, H_STR, a.Wp1, wr, wc, lane, acc);
  hid_epi(acc, a.b1, wr, wc, lane, sH);
  __syncthreads();
  zero4(acc);
  layer<4>(sH, H_STR, a.Wp2, wr, wc, lane, acc);
  hid_epi(acc, a.b2, wr, wc, lane, sA);
  __syncthreads();
  if (wc == 0){
    f32x4 a3 = {0.f, 0.f, 0.f, 0.f};
    const int row = wr*16 + (lane & 15), kg = lane >> 4;
    #pragma unroll
    for (int kb = 0; kb < 4; ++kb){
      bf16x8 av = *(const bf16x8*)(sA + row*H_STR + kb*32 + kg*8);
      bf16x8 bv = *(const bf16x8*)(a.Wp3 + ((kb*64 + lane) << 3));
      a3 = mfma16(av, bv, a3);
    }
    const int cl = lane & 15, r0l = wr*16 + (lane >> 4)*4;
    if (cl < 3){
      #pragma unroll
      for (int r = 0; r < 4; ++r)
        a.out[(size_t)(n0 + r0l + r)*3 + cl] = a3[r] + a.b3[cl];
    }
  }
}

// -------------------- host --------------------
extern "C" void kernel_launch(void* const* d_in, const int* in_sizes, int n_in,
                              void* d_out, int out_size, void* d_ws, size_t ws_size,
                              hipStream_t stream){
  auto F = [&](int i){ return (const float*)d_in[i]; };
  const float* node_x   = F(0);
  const float* mesh_attr = F(1);
  const float* cont_attr = F(2);
  const int* mei = (const int*)d_in[39];
  const int* cei = (const int*)d_in[40];
  const int *msrc = mei, *mdst = mei + EM, *csrc = cei, *cdst = cei + EC;

  char* ws = (char*)d_ws;
  size_t off = 0;
  auto take = [&](size_t b)->void*{ void* p = ws + off; off += (b + 255) & ~(size_t)255; return p; };
  float* x_f32  = (float*)take((size_t)NNODES*LDIM*4);
  u16*   x_b16  = (u16*)  take((size_t)NNODES*LDIM*2);
  float* me_f32 = (float*)take((size_t)EM*LDIM*4);
  float* ce_f32 = (float*)take((size_t)EC*LDIM*4);
  u16*   wpack  = (u16*)  take((size_t)309248*2);
  int* cnt_m   = (int*)take((size_t)NNODES*4);      // cnt_m/cnt_c adjacent: one memset
  int* cnt_c   = (int*)take((size_t)NNODES*4);
  int* start_m = (int*)take((size_t)(NNODES+1)*4);
  int* start_c = (int*)take((size_t)(NNODES+1)*4);
  int* cur_m   = (int*)take((size_t)NNODES*4);
  int* cur_c   = (int*)take((size_t)NNODES*4);
  int* pos_m   = (int*)take((size_t)EM*4);
  int* pos_c   = (int*)take((size_t)EC*4);
  int* sp_m    = (int*)take((size_t)EM*4);
  int* dp_m    = (int*)take((size_t)EM*4);
  int* sp_c    = (int*)take((size_t)EC*4);
  int* dp_c    = (int*)take((size_t)EC*4);

  // {d_in idx, K_raw, N_raw, K_pad, N_pad}
  static const int tbl[18][5] = {
    {3,12,128,32,128},{5,128,128,128,128},{7,128,128,128,128},      // ne
    {9,7,128,32,128},{11,128,128,128,128},{13,128,128,128,128},     // me
    {15,4,128,32,128},{17,128,128,128,128},{19,128,128,128,128},    // ce
    {21,384,128,384,128},{23,128,128,128,128},{25,128,128,128,128}, // pe
    {27,384,128,384,128},{29,128,128,128,128},{31,128,128,128,128}, // pn
    {33,128,128,128,128},{35,128,128,128,128},{37,128,3,128,16}};   // de
  PackArgs pa; int eo = 0; int offs[18];
  for (int i = 0; i < 18; ++i){
    offs[i] = eo;
    pa.d[i].src = F(tbl[i][0]);
    pa.d[i].K_raw = tbl[i][1];
    pa.d[i].N_raw = tbl[i][2];
    pa.d[i].NF = tbl[i][4] / 16;
    pa.d[i].elem_off = eo;
    eo += tbl[i][3] * tbl[i][4];
  }
  pa.total = eo;  // 309248
  pack_weights<<<dim3(eo/256), dim3(256), 0, stream>>>(pa, wpack);

  // CSR build (per call; edge indices are constant inputs)
  size_t cnt_span = ((char*)cnt_c - (char*)cnt_m) + (size_t)NNODES*4;
  hipMemsetAsync(cnt_m, 0, cnt_span, stream);
  hist_kernel<<<dim3((EM + EC + 255)/256), dim3(256), 0, stream>>>(mdst, cdst, cnt_m, cnt_c);
  ScanArgs sa{cnt_m, cnt_c, start_m, start_c, cur_m, cur_c};
  scan_kernel<<<dim3(2), dim3(256), 0, stream>>>(sa);
  scatter_kernel<<<dim3((EM + EC + 255)/256), dim3(256), 0, stream>>>(mdst, cdst, cur_m, cur_c, pos_m, pos_c);
  permsd_kernel<<<dim3((EM + EC + 255)/256), dim3(256), 0, stream>>>(msrc, mdst, pos_m, csrc, cdst, pos_c,
                                                                     sp_m, dp_m, sp_c, dp_c);

  EncArgs en{node_x, 12, wpack+offs[0], wpack+offs[1], wpack+offs[2], F(4), F(6), F(8), x_f32, x_b16, nullptr};
  enc_kernel<<<dim3(NNODES/MT), dim3(256), 0, stream>>>(en);
  EncArgs em{mesh_attr, 7, wpack+offs[3], wpack+offs[4], wpack+offs[5], F(10), F(12), F(14), me_f32, nullptr, pos_m};
  enc_kernel<<<dim3(EM/MT), dim3(256), 0, stream>>>(em);
  EncArgs ec{cont_attr, 4, wpack+offs[6], wpack+offs[7], wpack+offs[8], F(16), F(18), F(20), ce_f32, nullptr, pos_c};
  enc_kernel<<<dim3(EC/MT), dim3(256), 0, stream>>>(ec);

  EdgeArgs ea;
  ea.Wp1 = wpack+offs[9]; ea.Wp2 = wpack+offs[10]; ea.Wp3 = wpack+offs[11];
  ea.b1 = F(22); ea.b2 = F(24); ea.b3 = F(26);
  ea.x_b16 = x_b16;
  ea.sp_m = sp_m; ea.dp_m = dp_m; ea.sp_c = sp_c; ea.dp_c = dp_c;
  ea.me_f32 = me_f32; ea.ce_f32 = ce_f32;
  ea.mesh_blocks = EM/MT2;                                  // 1875

  NodeArgs na;
  na.Wp1 = wpack+offs[12]; na.Wp2 = wpack+offs[13]; na.Wp3 = wpack+offs[14];
  na.b1 = F(28); na.b2 = F(30); na.b3 = F(32);
  na.x_b16_in = x_b16;
  na.me_f32 = me_f32; na.ce_f32 = ce_f32;
  na.start_m = start_m; na.start_c = start_c;
  na.x_f32 = x_f32; na.x_b16_out = x_b16;

  const int edge_blocks = EM/MT2 + (EC + MT2 - 1)/MT2;      // 1875 + 313
  const int node_blocks = NNODES/MT;                        // 625
  for (int s = 0; s < 10; ++s){
    edge_kernel<<<dim3(edge_blocks), dim3(512), 0, stream>>>(ea);
    node_kernel<<<dim3(node_blocks), dim3(512), 0, stream>>>(na);
  }

  DecArgs da{wpack+offs[15], wpack+offs[16], wpack+offs[17], F(34), F(36), F(38), x_b16, (float*)d_out};
  dec_kernel<<<dim3(NNODES/MT), dim3(256), 0, stream>>>(da);
}

// Round 13
// 1150.341 us; speedup vs baseline: 1.0887x; 1.0001x over previous
//
#include <hip/hip_runtime.h>
#include <stdint.h>

typedef unsigned short u16;
typedef __attribute__((ext_vector_type(8))) short bf16x8;   // 8 bf16 = 4 VGPRs (MFMA A/B frag)
typedef __attribute__((ext_vector_type(4))) float f32x4;    // MFMA C/D frag

#define NNODES 20000
#define EM 120000
#define EC 20000
#define LDIM 128
#define MT 32          // rows per block (enc/dec/node kernels)
#define MT2 64         // rows per block (edge kernel, 512 threads)
#define A_STR 392      // concat LDS stride in shorts (384+8 pad -> 4-bank shift/row)
#define X_STR 264      // edge x-stage stride (256+8 pad -> 4-bank shift/row)
#define H_STR 136      // 128+8 pad
#define D_STR 132      // f32 delta stride (128+4 pad)

__device__ __forceinline__ u16 f2bf(float f){
  uint32_t b = __float_as_uint(f);
  b += 0x7FFF + ((b >> 16) & 1);          // RNE
  return (u16)(b >> 16);
}

__device__ __forceinline__ f32x4 mfma16(bf16x8 a, bf16x8 b, f32x4 c){
  return __builtin_amdgcn_mfma_f32_16x16x32_bf16(a, b, c, 0, 0, 0);
}

// ================= 256-thread (enc/dec) MLP primitives: wave tile 16x64 =================
template<int KB>
__device__ __forceinline__ void layer(const u16* sIn, int in_str, const u16* Wp,
                                      int wr, int wc, int lane, f32x4 acc[4]){
  const int row = wr*16 + (lane & 15);
  const int kg  = lane >> 4;
  #pragma unroll
  for (int kb = 0; kb < KB; ++kb){
    bf16x8 a = *(const bf16x8*)(sIn + row*in_str + kb*32 + kg*8);
    const u16* wb = Wp + (((kb*8 + wc*4)*64 + lane) << 3);
    #pragma unroll
    for (int nf = 0; nf < 4; ++nf){
      bf16x8 b = *(const bf16x8*)(wb + (nf << 9));
      acc[nf] = mfma16(a, b, acc[nf]);
    }
  }
}

__device__ __forceinline__ void hid_epi(f32x4 acc[4], const float* bias,
                                        int wr, int wc, int lane, u16* sOut){
  const int cl = lane & 15;
  const int r0 = wr*16 + (lane >> 4)*4;
  #pragma unroll
  for (int nf = 0; nf < 4; ++nf){
    int col = wc*64 + nf*16 + cl;
    float bv = bias[col];
    #pragma unroll
    for (int r = 0; r < 4; ++r){
      float v = acc[nf][r] + bv;
      sOut[(r0 + r)*H_STR + col] = f2bf(v > 0.f ? v : 0.f);
    }
  }
}

__device__ __forceinline__ void zero4(f32x4 acc[4]){
  const f32x4 vz = {0.f, 0.f, 0.f, 0.f};
  #pragma unroll
  for (int i = 0; i < 4; ++i) acc[i] = vz;
}

// ================= 512-thread edge MLP primitives: wave tile 32x32 =================
template<int KB, int STR>
__device__ __forceinline__ void layer64(const u16* sIn, const u16* Wp,
                                        int wr, int wc, int lane, f32x4 acc[2][2]){
  const int r0 = wr*32 + (lane & 15);
  const int kg = lane >> 4;
  const u16* a0p = sIn + r0*STR + kg*8;
  const u16* a1p = a0p + 16*STR;
  const u16* wb  = Wp + (((wc*2)*64 + lane) << 3);
  #pragma unroll
  for (int kb = 0; kb < KB; ++kb){
    bf16x8 a0 = *(const bf16x8*)(a0p + kb*32);
    bf16x8 a1 = *(const bf16x8*)(a1p + kb*32);
    const u16* wk = wb + kb*4096;            // kb * 8 frags * 64 lanes * 8 shorts
    bf16x8 b0 = *(const bf16x8*)(wk);
    bf16x8 b1 = *(const bf16x8*)(wk + 512);
    acc[0][0] = mfma16(a0, b0, acc[0][0]);
    acc[1][0] = mfma16(a1, b0, acc[1][0]);
    acc[0][1] = mfma16(a0, b1, acc[0][1]);
    acc[1][1] = mfma16(a1, b1, acc[1][1]);
  }
}

template<int STR>
__device__ __forceinline__ void hid_epi64(f32x4 acc[2][2], const float* bias,
                                          int wr, int wc, int lane, u16* sOut){
  const int cl = lane & 15;
  const int rq = (lane >> 4)*4;
  #pragma unroll
  for (int rf = 0; rf < 2; ++rf){
    int r0 = wr*32 + rf*16 + rq;
    #pragma unroll
    for (int nf = 0; nf < 2; ++nf){
      int col = wc*32 + nf*16 + cl;
      float bv = bias[col];
      #pragma unroll
      for (int r = 0; r < 4; ++r){
        float v = acc[rf][nf][r] + bv;
        sOut[(r0 + r)*STR + col] = f2bf(v > 0.f ? v : 0.f);
      }
    }
  }
}

__device__ __forceinline__ void zero22(f32x4 acc[2][2]){
  const f32x4 vz = {0.f, 0.f, 0.f, 0.f};
  acc[0][0] = vz; acc[0][1] = vz; acc[1][0] = vz; acc[1][1] = vz;
}

// ================= 512-thread node MLP primitives: wave tile 16x32 =================
template<int KB, int STR>
__device__ __forceinline__ void layer32(const u16* sIn, const u16* Wp,
                                        int wr, int wc, int lane, f32x4 acc[2]){
  const int r0 = wr*16 + (lane & 15);
  const int kg = lane >> 4;
  const u16* a0p = sIn + r0*STR + kg*8;
  const u16* wb  = Wp + (((wc*2)*64 + lane) << 3);
  #pragma unroll
  for (int kb = 0; kb < KB; ++kb){
    bf16x8 a0 = *(const bf16x8*)(a0p + kb*32);
    const u16* wk = wb + kb*4096;
    bf16x8 b0 = *(const bf16x8*)(wk);
    bf16x8 b1 = *(const bf16x8*)(wk + 512);
    acc[0] = mfma16(a0, b0, acc[0]);
    acc[1] = mfma16(a0, b1, acc[1]);
  }
}

template<int STR>
__device__ __forceinline__ void hid_epi32(f32x4 acc[2], const float* bias,
                                          int wr, int wc, int lane, u16* sOut){
  const int cl = lane & 15;
  const int r0 = wr*16 + (lane >> 4)*4;
  #pragma unroll
  for (int nf = 0; nf < 2; ++nf){
    int col = wc*32 + nf*16 + cl;
    float bv = bias[col];
    #pragma unroll
    for (int r = 0; r < 4; ++r){
      float v = acc[nf][r] + bv;
      sOut[(r0 + r)*STR + col] = f2bf(v > 0.f ? v : 0.f);
    }
  }
}

// -------------------- weight packing --------------------
struct PackDesc { const float* src; int K_raw, N_raw, NF, elem_off; };
struct PackArgs { PackDesc d[18]; int total; };

__global__ __launch_bounds__(256) void pack_weights(PackArgs pa, u16* dst){
  int idx = blockIdx.x*256 + threadIdx.x;
  if (idx >= pa.total) return;
  int di = 0;
  #pragma unroll
  for (int i = 1; i < 18; ++i) if (idx >= pa.d[i].elem_off) di = i;
  PackDesc dd = pa.d[di];
  int e = idx - dd.elem_off;
  int f = e >> 9, lane = (e >> 3) & 63, j = e & 7;
  int kb = f / dd.NF, nf = f % dd.NF;
  int k = kb*32 + (lane >> 4)*8 + j;
  int n = nf*16 + (lane & 15);
  float v = (k < dd.K_raw && n < dd.N_raw) ? dd.src[k*dd.N_raw + n] : 0.f;
  dst[idx] = f2bf(v);
}

// -------------------- CSR build (dst-grouped edge order) --------------------
__global__ __launch_bounds__(256) void hist_kernel(const int* mdst, const int* cdst,
                                                   int* cnt_m, int* cnt_c){
  int i = blockIdx.x*256 + threadIdx.x;
  if (i < EM) atomicAdd(&cnt_m[mdst[i]], 1);
  else if (i < EM + EC) atomicAdd(&cnt_c[cdst[i - EM]], 1);
}

struct ScanArgs { const int *cnt_m, *cnt_c; int *start_m, *start_c, *cur_m, *cur_c; };

__global__ __launch_bounds__(256) void scan_kernel(ScanArgs a){
  const int n = NNODES;
  const int* cnt = blockIdx.x == 0 ? a.cnt_m : a.cnt_c;
  int* start     = blockIdx.x == 0 ? a.start_m : a.start_c;
  int* cur       = blockIdx.x == 0 ? a.cur_m : a.cur_c;
  __shared__ int part[256];
  __shared__ int base[257];
  int t = threadIdx.x;
  const int per = (n + 255) / 256;
  int lo = t*per, hi = min(n, lo + per);
  int s = 0;
  for (int j = lo; j < hi; ++j) s += cnt[j];
  part[t] = s;
  __syncthreads();
  if (t == 0){
    int run = 0;
    for (int i = 0; i < 256; ++i){ base[i] = run; run += part[i]; }
    base[256] = run;
  }
  __syncthreads();
  int run = base[t];
  for (int j = lo; j < hi; ++j){ start[j] = run; cur[j] = run; run += cnt[j]; }
  if (t == 255) start[n] = base[256];
}

// pos[i] = CSR slot of original edge i
__global__ __launch_bounds__(256) void scatter_kernel(const int* mdst, const int* cdst,
                                                      int* cur_m, int* cur_c,
                                                      int* pos_m, int* pos_c){
  int i = blockIdx.x*256 + threadIdx.x;
  if (i < EM){
    int p = atomicAdd(&cur_m[mdst[i]], 1);
    pos_m[i] = p;
  } else if (i < EM + EC){
    int e = i - EM;
    int p = atomicAdd(&cur_c[cdst[e]], 1);
    pos_c[e] = p;
  }
}

// sp/dp[slot] = src/dst of the edge stored at that CSR slot (contiguous for edge kernel)
__global__ __launch_bounds__(256) void permsd_kernel(const int* msrc, const int* mdst, const int* pos_m,
                                                     const int* csrc, const int* cdst, const int* pos_c,
                                                     int* sp_m, int* dp_m, int* sp_c, int* dp_c){
  int i = blockIdx.x*256 + threadIdx.x;
  if (i < EM){
    int p = pos_m[i];
    sp_m[p] = msrc[i]; dp_m[p] = mdst[i];
  } else if (i < EM + EC){
    int e = i - EM;
    int p = pos_c[e];
    sp_c[p] = csrc[e]; dp_c[p] = cdst[e];
  }
}

// -------------------- encoder: out[perm[m]] = MLP(in[m]) --------------------
struct EncArgs {
  const float* in; int Kraw;
  const u16 *Wp1, *Wp2, *Wp3;
  const float *b1, *b2, *b3;
  float* out_f32; u16* out_b16;   // out_b16 nullable
  const int* perm;                // nullable: out row = perm ? perm[m] : m
};

__global__ __launch_bounds__(256) void enc_kernel(EncArgs a){
  __shared__ u16 sA[MT*A_STR];
  __shared__ u16 sH[MT*H_STR];
  const int tid = threadIdx.x, lane = tid & 63, w = tid >> 6, wr = w & 1, wc = w >> 1;
  const int m0 = blockIdx.x * MT;
  for (int i = tid; i < MT*32; i += 256){
    int row = i >> 5, c = i & 31;
    float v = (c < a.Kraw) ? a.in[(size_t)(m0 + row)*a.Kraw + c] : 0.f;
    sA[row*A_STR + c] = f2bf(v);
  }
  __syncthreads();
  f32x4 acc[4]; zero4(acc);
  layer<1>(sA, A_STR, a.Wp1, wr, wc, lane, acc);
  hid_epi(acc, a.b1, wr, wc, lane, sH);
  __syncthreads();
  zero4(acc);
  layer<4>(sH, H_STR, a.Wp2, wr, wc, lane, acc);
  hid_epi(acc, a.b2, wr, wc, lane, sA);    // h2 reuses sA
  __syncthreads();
  zero4(acc);
  layer<4>(sA, H_STR, a.Wp3, wr, wc, lane, acc);
  const int cl = lane & 15, r0l = wr*16 + (lane >> 4)*4;
  #pragma unroll
  for (int nf = 0; nf < 4; ++nf){
    int col = wc*64 + nf*16 + cl;
    float bv = a.b3[col];
    #pragma unroll
    for (int r = 0; r < 4; ++r){
      int m = m0 + r0l + r;
      int om = a.perm ? a.perm[m] : m;
      float v = acc[nf][r] + bv;
      a.out_f32[(size_t)om*LDIM + col] = v;
      if (a.out_b16) a.out_b16[(size_t)om*LDIM + col] = f2bf(v);
    }
  }
}

// -------------------- edge update: split-L1 (33.8 KB LDS, 4 blocks/CU) + CSR storage --------------------
// L1a (kb0..7 over x), barrier, feat overwrites cols 0..127, L1b (kb8..11) same acc,
// same kb order => bit-identical numerics. (512,6): no VGPR cap -> no spills (R11 lesson).
struct EdgeArgs {
  const u16 *Wp1, *Wp2, *Wp3;
  const float *b1, *b2, *b3;
  const u16* x_b16;
  const int *sp_m, *dp_m, *sp_c, *dp_c;
  float *me_f32, *ce_f32;
  int mesh_blocks;
};

__global__ __launch_bounds__(512, 6) void edge_kernel(EdgeArgs a){
  __shared__ u16 sCat[MT2*X_STR];   // 33792 B: x 0..255; then feat->0..127, h1->128..255, h2->0..127; f32 delta aliases all
  const int tid = threadIdx.x, lane = tid & 63, w = tid >> 6, wr = w & 1, wc = w >> 1;
  const bool mesh = (int)blockIdx.x < a.mesh_blocks;
  const int e0 = (mesh ? (int)blockIdx.x : (int)blockIdx.x - a.mesh_blocks) * MT2;
  const int E = mesh ? EM : EC;
  const int* sp = mesh ? a.sp_m : a.sp_c;
  const int* dp = mesh ? a.dp_m : a.dp_c;
  float* ff = mesh ? a.me_f32 : a.ce_f32;

  // ---- early feat f32 load (independent; latency hides under x staging) ----
  const int srow = tid >> 3, sj = tid & 7;
  int se = e0 + srow; if (se >= E) se = E - 1;
  const f32x4* fp = (const f32x4*)(ff + (size_t)se*LDIM + sj*16);
  f32x4 p0 = fp[0], p1 = fp[1], p2 = fp[2], p3 = fp[3];

  // ---- stage x[src], x[dst]: 64 rows x 32 bf16x8 chunks, coalesced (CSR sp/dp) ----
  #pragma unroll
  for (int i = tid; i < MT2*32; i += 512){
    int row = i >> 5, c = i & 31;
    int e = e0 + row; if (e >= E) e = E - 1;
    const u16* xp = (c < 16) ? a.x_b16 + (size_t)sp[e]*LDIM + c*8
                             : a.x_b16 + (size_t)dp[e]*LDIM + (c-16)*8;
    *(bf16x8*)(sCat + row*X_STR + c*8) = *(const bf16x8*)xp;
  }
  __syncthreads();

  f32x4 acc[2][2]; zero22(acc);
  layer64<8, X_STR>(sCat, a.Wp1, wr, wc, lane, acc);     // L1a: kb 0..7 (x part)
  __syncthreads();                                        // all waves done reading x

  { // feat f32 -> bf16 -> cols 0..127 (overwrites dead x-low region)
    bf16x8 t0, t1;
    #pragma unroll
    for (int k = 0; k < 4; ++k){
      t0[k] = (short)f2bf(p0[k]); t0[k+4] = (short)f2bf(p1[k]);
      t1[k] = (short)f2bf(p2[k]); t1[k+4] = (short)f2bf(p3[k]);
    }
    *(bf16x8*)(sCat + srow*X_STR + sj*16) = t0;
    *(bf16x8*)(sCat + srow*X_STR + sj*16 + 8) = t1;
  }
  __syncthreads();

  layer64<4, X_STR>(sCat, a.Wp1 + 8*4096, wr, wc, lane, acc);  // L1b: kb 8..11 (feat part)
  hid_epi64<X_STR>(acc, a.b1, wr, wc, lane, sCat + 128);       // h1 -> cols 128..255 (disjoint from feat reads)
  __syncthreads();
  zero22(acc);
  layer64<4, X_STR>(sCat + 128, a.Wp2, wr, wc, lane, acc);
  hid_epi64<X_STR>(acc, a.b2, wr, wc, lane, sCat);             // h2 -> cols 0..127 (disjoint from h1 reads)
  __syncthreads();
  zero22(acc);
  layer64<4, X_STR>(sCat, a.Wp3, wr, wc, lane, acc);
  __syncthreads();                                             // all h2 reads done; delta may overwrite

  // ---- delta (acc + b3) -> f32 LDS, then residual RMW from registered f32 ----
  float* dd = (float*)sCat;                                    // [64][D_STR] f32 = 33792 B exactly
  {
    const int cl = lane & 15, rq = (lane >> 4)*4;
    #pragma unroll
    for (int rf = 0; rf < 2; ++rf){
      #pragma unroll
      for (int nf = 0; nf < 2; ++nf){
        int col = wc*32 + nf*16 + cl;
        float bv = a.b3[col];
        #pragma unroll
        for (int r = 0; r < 4; ++r)
          dd[(wr*32 + rf*16 + rq + r)*D_STR + col] = acc[rf][nf][r] + bv;
      }
    }
  }
  __syncthreads();
  if (e0 + srow < E){
    float* op = ff + (size_t)(e0 + srow)*LDIM + sj*16;
    const f32x4* dp_ = (const f32x4*)(dd + srow*D_STR + sj*16);
    f32x4 n0 = p0 + dp_[0], n1 = p1 + dp_[1], n2 = p2 + dp_[2], n3 = p3 + dp_[3];
    ((f32x4*)op)[0] = n0; ((f32x4*)op)[1] = n1; ((f32x4*)op)[2] = n2; ((f32x4*)op)[3] = n3;
  }
}

// -------------------- node update: contiguous CSR gather (2-unrolled) + MLP --------------------
struct NodeArgs {
  const u16 *Wp1, *Wp2, *Wp3;
  const float *b1, *b2, *b3;
  const u16* x_b16_in;
  const float *me_f32, *ce_f32;
  const int *start_m, *start_c;
  float* x_f32; u16* x_b16_out;
};

__global__ __launch_bounds__(512, 6) void node_kernel(NodeArgs a){
  __shared__ u16 sA[MT*A_STR];   // concat: x 0..127 | agg_m 128..255 | agg_c 256..383; h1 aliases 256.., h2 aliases 0..
  const int tid = threadIdx.x, lane = tid & 63, w = tid >> 6, wr = w & 1, wc = w >> 1;
  const int n0 = blockIdx.x * MT;        // 20000/32 = 625 blocks exact, no bounds checks

  // stage x (bf16 mirror): 32 rows x 16 chunks = 512, one per thread
  {
    int row = tid >> 4, ch = tid & 15;
    *(bf16x8*)(sA + row*A_STR + ch*8) =
        *(const bf16x8*)(a.x_b16_in + (size_t)(n0+row)*LDIM + ch*8);
  }
  // CSR gather-mean, CONTIGUOUS rows, 2-unrolled (add order preserved): 16 thr/node, 8 cols each
  {
    const int r = tid >> 4, c0 = (tid & 15) * 8;
    const int n = n0 + r;
    // mesh -> cols 128..255
    {
      int s = a.start_m[n], e = a.start_m[n+1];
      f32x4 a0{0,0,0,0}, a1{0,0,0,0};
      int j = s;
      for (; j + 1 < e; j += 2){
        const f32x4* pA = (const f32x4*)(a.me_f32 + (size_t)j*LDIM + c0);
        const f32x4* pB = (const f32x4*)(a.me_f32 + (size_t)(j+1)*LDIM + c0);
        f32x4 qA0 = pA[0], qA1 = pA[1], qB0 = pB[0], qB1 = pB[1];
        a0 += qA0; a1 += qA1;
        a0 += qB0; a1 += qB1;
      }
      if (j < e){
        const f32x4* p = (const f32x4*)(a.me_f32 + (size_t)j*LDIM + c0);
        a0 += p[0]; a1 += p[1];
      }
      float inv = 1.f / fmaxf((float)(e - s), 1.f);
      bf16x8 t;
      #pragma unroll
      for (int k = 0; k < 4; ++k){ t[k] = (short)f2bf(a0[k]*inv); t[k+4] = (short)f2bf(a1[k]*inv); }
      *(bf16x8*)(sA + r*A_STR + 128 + c0) = t;
    }
    // contact -> cols 256..383
    {
      int s = a.start_c[n], e = a.start_c[n+1];
      f32x4 a0{0,0,0,0}, a1{0,0,0,0};
      int j = s;
      for (; j + 1 < e; j += 2){
        const f32x4* pA = (const f32x4*)(a.ce_f32 + (size_t)j*LDIM + c0);
        const f32x4* pB = (const f32x4*)(a.ce_f32 + (size_t)(j+1)*LDIM + c0);
        f32x4 qA0 = pA[0], qA1 = pA[1], qB0 = pB[0], qB1 = pB[1];
        a0 += qA0; a1 += qA1;
        a0 += qB0; a1 += qB1;
      }
      if (j < e){
        const f32x4* p = (const f32x4*)(a.ce_f32 + (size_t)j*LDIM + c0);
        a0 += p[0]; a1 += p[1];
      }
      float inv = 1.f / fmaxf((float)(e - s), 1.f);
      bf16x8 t;
      #pragma unroll
      for (int k = 0; k < 4; ++k){ t[k] = (short)f2bf(a0[k]*inv); t[k+4] = (short)f2bf(a1[k]*inv); }
      *(bf16x8*)(sA + r*A_STR + 256 + c0) = t;
    }
  }
  __syncthreads();

  f32x4 acc[2]; acc[0] = f32x4{0,0,0,0}; acc[1] = f32x4{0,0,0,0};
  layer32<12, A_STR>(sA, a.Wp1, wr, wc, lane, acc);
  __syncthreads();                                   // all waves done reading concat
  hid_epi32<A_STR>(acc, a.b1, wr, wc, lane, sA + 256);   // h1 -> cols 256..383
  __syncthreads();
  acc[0] = f32x4{0,0,0,0}; acc[1] = f32x4{0,0,0,0};
  layer32<4, A_STR>(sA + 256, a.Wp2, wr, wc, lane, acc);
  hid_epi32<A_STR>(acc, a.b2, wr, wc, lane, sA);         // h2 -> cols 0..127 (disjoint)
  __syncthreads();
  acc[0] = f32x4{0,0,0,0}; acc[1] = f32x4{0,0,0,0};
  layer32<4, A_STR>(sA, a.Wp3, wr, wc, lane, acc);

  const int cl = lane & 15, rq = (lane >> 4)*4;
  #pragma unroll
  for (int r = 0; r < 4; ++r){
    int n = n0 + wr*16 + rq + r;
    #pragma unroll
    for (int nf = 0; nf < 2; ++nf){
      int col = wc*32 + nf*16 + cl;
      float nv = a.x_f32[(size_t)n*LDIM + col] + acc[nf][r] + a.b3[col];
      a.x_f32[(size_t)n*LDIM + col] = nv;
      a.x_b16_out[(size_t)n*LDIM + col] = f2bf(nv);
    }
  }
}

// -------------------- decoder: out[N,3] --------------------
struct DecArgs {
  const u16 *Wp1, *Wp2, *Wp3;
  const float *b1, *b2, *b3;
  const u16* x_b16; float* out;
};

__global__ __launch_bounds__(256) void dec_kernel(DecArgs a){
  __shared__ u16 sA[MT*A_STR];
  __shared__ u16 sH[MT*H_STR];
  const int tid = threadIdx.x, lane = tid & 63, w = tid >> 6, wr = w & 1, wc = w >> 1;
  const int n0 = blockIdx.x * MT;
  for (int i = tid; i < MT*16; i += 256){
    int row = i >> 4, ch = i & 15;
    *(bf16x8*)(sA + row*H_STR + ch*8) = *(const bf16x8*)(a.x_b16 + (size_t)(n0+row)*LDIM + ch*8);
  }
  __syncthreads();
  f32x4 acc[4]; zero4(acc);
  layer<4>(sA, H_STR, a.Wp1, wr, wc, lane, acc);
  hid_epi(acc, a.b1, wr, wc, lane, sH);
  __syncthreads();
  zero4(acc);
  layer<4>(sH, H_STR, a.Wp2, wr, wc, lane, acc);
  hid_epi(acc, a.b2, wr, wc, lane, sA);
  __syncthreads();
  if (wc == 0){
    f32x4 a3 = {0.f, 0.f, 0.f, 0.f};
    const int row = wr*16 + (lane & 15), kg = lane >> 4;
    #pragma unroll
    for (int kb = 0; kb < 4; ++kb){
      bf16x8 av = *(const bf16x8*)(sA + row*H_STR + kb*32 + kg*8);
      bf16x8 bv = *(const bf16x8*)(a.Wp3 + ((kb*64 + lane) << 3));
      a3 = mfma16(av, bv, a3);
    }
    const int cl = lane & 15, r0l = wr*16 + (lane >> 4)*4;
    if (cl < 3){
      #pragma unroll
      for (int r = 0; r < 4; ++r)
        a.out[(size_t)(n0 + r0l + r)*3 + cl] = a3[r] + a.b3[cl];
    }
  }
}

// -------------------- host --------------------
extern "C" void kernel_launch(void* const* d_in, const int* in_sizes, int n_in,
                              void* d_out, int out_size, void* d_ws, size_t ws_size,
                              hipStream_t stream){
  auto F = [&](int i){ return (const float*)d_in[i]; };
  const float* node_x   = F(0);
  const float* mesh_attr = F(1);
  const float* cont_attr = F(2);
  const int* mei = (const int*)d_in[39];
  const int* cei = (const int*)d_in[40];
  const int *msrc = mei, *mdst = mei + EM, *csrc = cei, *cdst = cei + EC;

  char* ws = (char*)d_ws;
  size_t off = 0;
  auto take = [&](size_t b)->void*{ void* p = ws + off; off += (b + 255) & ~(size_t)255; return p; };
  float* x_f32  = (float*)take((size_t)NNODES*LDIM*4);
  u16*   x_b16  = (u16*)  take((size_t)NNODES*LDIM*2);
  float* me_f32 = (float*)take((size_t)EM*LDIM*4);
  float* ce_f32 = (float*)take((size_t)EC*LDIM*4);
  u16*   wpack  = (u16*)  take((size_t)309248*2);
  int* cnt_m   = (int*)take((size_t)NNODES*4);      // cnt_m/cnt_c adjacent: one memset
  int* cnt_c   = (int*)take((size_t)NNODES*4);
  int* start_m = (int*)take((size_t)(NNODES+1)*4);
  int* start_c = (int*)take((size_t)(NNODES+1)*4);
  int* cur_m   = (int*)take((size_t)NNODES*4);
  int* cur_c   = (int*)take((size_t)NNODES*4);
  int* pos_m   = (int*)take((size_t)EM*4);
  int* pos_c   = (int*)take((size_t)EC*4);
  int* sp_m    = (int*)take((size_t)EM*4);
  int* dp_m    = (int*)take((size_t)EM*4);
  int* sp_c    = (int*)take((size_t)EC*4);
  int* dp_c    = (int*)take((size_t)EC*4);

  // {d_in idx, K_raw, N_raw, K_pad, N_pad}
  static const int tbl[18][5] = {
    {3,12,128,32,128},{5,128,128,128,128},{7,128,128,128,128},      // ne
    {9,7,128,32,128},{11,128,128,128,128},{13,128,128,128,128},     // me
    {15,4,128,32,128},{17,128,128,128,128},{19,128,128,128,128},    // ce
    {21,384,128,384,128},{23,128,128,128,128},{25,128,128,128,128}, // pe
    {27,384,128,384,128},{29,128,128,128,128},{31,128,128,128,128}, // pn
    {33,128,128,128,128},{35,128,128,128,128},{37,128,3,128,16}};   // de
  PackArgs pa; int eo = 0; int offs[18];
  for (int i = 0; i < 18; ++i){
    offs[i] = eo;
    pa.d[i].src = F(tbl[i][0]);
    pa.d[i].K_raw = tbl[i][1];
    pa.d[i].N_raw = tbl[i][2];
    pa.d[i].NF = tbl[i][4] / 16;
    pa.d[i].elem_off = eo;
    eo += tbl[i][3] * tbl[i][4];
  }
  pa.total = eo;  // 309248
  pack_weights<<<dim3(eo/256), dim3(256), 0, stream>>>(pa, wpack);

  // CSR build (per call; edge indices are constant inputs)
  size_t cnt_span = ((char*)cnt_c - (char*)cnt_m) + (size_t)NNODES*4;
  hipMemsetAsync(cnt_m, 0, cnt_span, stream);
  hist_kernel<<<dim3((EM + EC + 255)/256), dim3(256), 0, stream>>>(mdst, cdst, cnt_m, cnt_c);
  ScanArgs sa{cnt_m, cnt_c, start_m, start_c, cur_m, cur_c};
  scan_kernel<<<dim3(2), dim3(256), 0, stream>>>(sa);
  scatter_kernel<<<dim3((EM + EC + 255)/256), dim3(256), 0, stream>>>(mdst, cdst, cur_m, cur_c, pos_m, pos_c);
  permsd_kernel<<<dim3((EM + EC + 255)/256), dim3(256), 0, stream>>>(msrc, mdst, pos_m, csrc, cdst, pos_c,
                                                                     sp_m, dp_m, sp_c, dp_c);

  EncArgs en{node_x, 12, wpack+offs[0], wpack+offs[1], wpack+offs[2], F(4), F(6), F(8), x_f32, x_b16, nullptr};
  enc_kernel<<<dim3(NNODES/MT), dim3(256), 0, stream>>>(en);
  EncArgs em{mesh_attr, 7, wpack+offs[3], wpack+offs[4], wpack+offs[5], F(10), F(12), F(14), me_f32, nullptr, pos_m};
  enc_kernel<<<dim3(EM/MT), dim3(256), 0, stream>>>(em);
  EncArgs ec{cont_attr, 4, wpack+offs[6], wpack+offs[7], wpack+offs[8], F(16), F(18), F(20), ce_f32, nullptr, pos_c};
  enc_kernel<<<dim3(EC/MT), dim3(256), 0, stream>>>(ec);

  EdgeArgs ea;
  ea.Wp1 = wpack+offs[9]; ea.Wp2 = wpack+offs[10]; ea.Wp3 = wpack+offs[11];
  ea.b1 = F(22); ea.b2 = F(24); ea.b3 = F(26);
  ea.x_b16 = x_b16;
  ea.sp_m = sp_m; ea.dp_m = dp_m; ea.sp_c = sp_c; ea.dp_c = dp_c;
  ea.me_f32 = me_f32; ea.ce_f32 = ce_f32;
  ea.mesh_blocks = EM/MT2;                                  // 1875

  NodeArgs na;
  na.Wp1 = wpack+offs[12]; na.Wp2 = wpack+offs[13]; na.Wp3 = wpack+offs[14];
  na.b1 = F(28); na.b2 = F(30); na.b3 = F(32);
  na.x_b16_in = x_b16;
  na.me_f32 = me_f32; na.ce_f32 = ce_f32;
  na.start_m = start_m; na.start_c = start_c;
  na.x_f32 = x_f32; na.x_b16_out = x_b16;

  const int edge_blocks = EM/MT2 + (EC + MT2 - 1)/MT2;      // 1875 + 313
  const int node_blocks = NNODES/MT;                        // 625
  for (int s = 0; s < 10; ++s){
    edge_kernel<<<dim3(edge_blocks), dim3(512), 0, stream>>>(ea);
    node_kernel<<<dim3(node_blocks), dim3(512), 0, stream>>>(na);
  }

  DecArgs da{wpack+offs[15], wpack+offs[16], wpack+offs[17], F(34), F(36), F(38), x_b16, (float*)d_out};
  dec_kernel<<<dim3(NNODES/MT), dim3(256), 0, stream>>>(da);
}